// Round 3
// baseline (397.296 us; speedup 1.0000x reference)
//
#include <hip/hip_runtime.h>
#include <math.h>

typedef __bf16 bf16_t;
typedef bf16_t bf16x8 __attribute__((ext_vector_type(8)));
typedef float  floatx4 __attribute__((ext_vector_type(4)));

constexpr int N_SEQ = 4096, BSZ = 4, CIN = 384, CDSSP = 64, CHID = 128, NBLK = 4;
constexpr int NTOK = BSZ * N_SEQ;                       // 16384
constexpr int TOK_PER_BLK = 32;
constexpr int MLP_BLOCKS  = NTOK / TOK_PER_BLK;         // 512 blocks, 4 waves each

// ---- wsb layout in 16-byte units (1 unit = 8 bf16), per matrix:
// hi plane (128*K8 units) || lo plane. Within a plane, element (j, k8) with
// nt=j>>4, col=j&15, kg=k8>>2, q=k8&3 lives at unit  nt*(16*K8) + kg*64 + col*4 + q.
// -> a wave's B-frag load for (nt,kg) is 64 lanes x 16 B CONTIGUOUS (1 KB).
constexpr int U_SIN   = 0;                 // W_in:   plane 6144 u, total 12288
constexpr int U_SINIT = 12288;             // W_init: total 12288
constexpr int U_DSSP  = 24576;             // W_dssp: plane 1024 u, total 2048
constexpr int U_W1    = 26624;             // 4 * 4096
constexpr int U_W2    = 43008;             // 4 * 4096
constexpr int U_END   = 59392;             // 950272 B
constexpr int BAND_OFF = U_END * 4;        // float index into d_ws for band arrays

__device__ __forceinline__ float softplus_f(float x) {
    return fmaxf(x, 0.f) + log1pf(expf(-fabsf(x)));
}
__device__ __forceinline__ unsigned short bf16_bits(bf16_t h) {
    union { bf16_t b; unsigned short u; } c; c.b = h; return c.u;
}
__device__ __forceinline__ bf16_t bits_bf16(unsigned int u) {
    union { unsigned short u; bf16_t b; } c; c.u = (unsigned short)u; return c.b;
}
__device__ __forceinline__ floatx4 mfma16(bf16x8 a, bf16x8 b, floatx4 c) {
    return __builtin_amdgcn_mfma_f32_16x16x32_bf16(a, b, c, 0, 0, 0);
}

// ---- prep: split weights into bf16 hi/lo, write coalesced-B-frag image ----
__global__ __launch_bounds__(256) void prep_weights(
    const float* __restrict__ Win, const float* __restrict__ Winit,
    const float* __restrict__ Wd,  const float* __restrict__ W1,
    const float* __restrict__ W2,  bf16_t* __restrict__ wsb)
{
    const int t = (int)blockIdx.x * 256 + (int)threadIdx.x;   // 0..29695
    const float* src; int K, hi_base, plane, u;
    if (t < 6144)       { src = Win;   K = CIN;   hi_base = U_SIN;   plane = 6144; u = t; }
    else if (t < 12288) { src = Winit; K = CIN;   hi_base = U_SINIT; plane = 6144; u = t - 6144; }
    else if (t < 13312) { src = Wd;    K = CDSSP; hi_base = U_DSSP;  plane = 1024; u = t - 12288; }
    else if (t < 21504) { const int tt = t - 13312, rb = tt >> 11; u = tt & 2047;
                          src = W1 + (size_t)rb * CHID * CHID; K = CHID;
                          hi_base = U_W1 + rb * 4096; plane = 2048; }
    else                { const int tt = t - 21504, rb = tt >> 11; u = tt & 2047;
                          src = W2 + (size_t)rb * CHID * CHID; K = CHID;
                          hi_base = U_W2 + rb * 4096; plane = 2048; }
    const int K8 = K >> 3;
    const int nt = u / (16 * K8);
    const int r  = u - nt * 16 * K8;
    const int kg = r >> 6, r2 = r & 63, c = r2 >> 2, qq = r2 & 3;
    const int j = nt * 16 + c, k8 = kg * 4 + qq;
    const float* sp = src + (size_t)j * K + k8 * 8;
    const float4 a = *(const float4*)sp;
    const float4 b = *(const float4*)(sp + 4);
    const float xs[8] = { a.x, a.y, a.z, a.w, b.x, b.y, b.z, b.w };
    bf16x8 vh, vl;
    #pragma unroll
    for (int i = 0; i < 8; ++i) {
        const float x = xs[i];
        const bf16_t h = (bf16_t)x;
        vh[i] = h; vl[i] = (bf16_t)(x - (float)h);
    }
    *(bf16x8*)(wsb + ((size_t)hi_base + u) * 8)         = vh;
    *(bf16x8*)(wsb + ((size_t)hi_base + plane + u) * 8) = vl;
}

// ---- B-frag register set: hi/lo for the wave's 2 nt tiles of one kg ----
struct BF2 { bf16x8 h[2]; bf16x8 l[2]; };

__device__ __forceinline__ void loadB(const bf16_t* __restrict__ plane, int K8,
                                      int kg, int ntbase, int col, int q, BF2& B) {
    const size_t lo  = (size_t)128 * K8 * 8;     // lo plane offset (elements)
    const size_t nts = (size_t)16 * K8 * 8;      // nt step (elements)
    const bf16_t* base = plane + (size_t)(kg * 64 + col * 4 + q) * 8
                               + (size_t)ntbase * nts;
    #pragma unroll
    for (int nt = 0; nt < 2; ++nt) {
        B.h[nt] = *(const bf16x8*)(base + nt * nts);
        B.l[nt] = *(const bf16x8*)(base + nt * nts + lo);
    }
}

__device__ __forceinline__ void mfma_step(const bf16x8 (&ahi)[2], const bf16x8 (&alo)[2],
                                          const BF2& B, floatx4 (&ac)[2][2]) {
    #pragma unroll
    for (int nt = 0; nt < 2; ++nt)
        #pragma unroll
        for (int mt = 0; mt < 2; ++mt) {
            ac[mt][nt] = mfma16(ahi[mt], B.h[nt], ac[mt][nt]);
            ac[mt][nt] = mfma16(alo[mt], B.h[nt], ac[mt][nt]);
            ac[mt][nt] = mfma16(ahi[mt], B.l[nt], ac[mt][nt]);
        }
}

__device__ __forceinline__ void packXA(const float4 (&X)[2][2],
                                       bf16x8 (&ahi)[2], bf16x8 (&alo)[2]) {
    #pragma unroll
    for (int mt = 0; mt < 2; ++mt) {
        const float xs[8] = { X[mt][0].x, X[mt][0].y, X[mt][0].z, X[mt][0].w,
                              X[mt][1].x, X[mt][1].y, X[mt][1].z, X[mt][1].w };
        #pragma unroll
        for (int i = 0; i < 8; ++i) {
            const float r = fmaxf(xs[i], 0.f);
            const bf16_t h = (bf16_t)r;
            ahi[mt][i] = h;
            alo[mt][i] = (bf16_t)(r - (float)h);
        }
    }
}

// A-frags from the block-shared Act plane (packed hi|lo per k)
__device__ __forceinline__ void ldsA(const uint32_t (*A)[132], int kg, int col, int q,
                                     bf16x8 (&ahi)[2], bf16x8 (&alo)[2]) {
    #pragma unroll
    for (int mt = 0; mt < 2; ++mt) {
        const uint32_t* p = &A[mt * 16 + col][kg * 32 + q * 8];
        const uint4 u0 = *(const uint4*)p;
        const uint4 u1 = *(const uint4*)(p + 4);
        const uint32_t uu[8] = { u0.x, u0.y, u0.z, u0.w, u1.x, u1.y, u1.z, u1.w };
        union { uint32_t u[4]; bf16x8 v; } ch, cl;
        #pragma unroll
        for (int i = 0; i < 4; ++i) {
            ch.u[i] = (uu[2*i] & 0xffffu) | (uu[2*i+1] << 16);
            cl.u[i] = (uu[2*i] >> 16) | (uu[2*i+1] & 0xffff0000u);
        }
        ahi[mt] = ch.v; alo[mt] = cl.v;
    }
}

// hidden matmul (K=128), rolled kg loop, B double-buffered
__device__ __forceinline__ void hidden_pass(const uint32_t (*A)[132],
    const bf16_t* __restrict__ plane, int ntbase, int col, int q, floatx4 (&ac)[2][2])
{
    BF2 B[2];
    loadB(plane, 16, 0, ntbase, col, q, B[0]);
    #pragma unroll 1
    for (int kg = 0; kg < 4; kg += 2) {
        loadB(plane, 16, kg + 1, ntbase, col, q, B[1]);
        bf16x8 ahi[2], alo[2];
        ldsA(A, kg, col, q, ahi, alo);
        mfma_step(ahi, alo, B[0], ac);
        if (kg + 2 < 4) loadB(plane, 16, kg + 2, ntbase, col, q, B[0]);
        ldsA(A, kg + 1, col, q, ahi, alo);
        mfma_step(ahi, alo, B[1], ac);
    }
}

// ---- MLP: 512 blocks x 4 waves; wave w owns output channels [w*32, w*32+32)
// (nt tiles 2w, 2w+1); all waves share one 32-token activation plane.
// 2048 waves total = 2 waves/SIMD -> load latency of one wave hides under
// the other's MFMA/VALU. Block-level weight traffic unchanged vs 2-wave. ----
__global__ __launch_bounds__(256) void mlp_kernel(
    const float* __restrict__ s, const float* __restrict__ s_init,
    const float* __restrict__ dssp,
    const float* __restrict__ b_in, const float* __restrict__ b_init,
    const float* __restrict__ b_dssp,
    const float* __restrict__ b1, const float* __restrict__ b2,
    const float* __restrict__ W_out, const float* __restrict__ b_out,
    const float* __restrict__ W_mult, const float* __restrict__ b_mult,
    const bf16_t* __restrict__ wsb, float* __restrict__ band)
{
    __shared__ uint32_t A[32][132];                 // 16.9 KB, block-shared act plane

    const int wid    = (int)threadIdx.x >> 6;       // 0..3
    const int lane   = (int)threadIdx.x & 63;
    const int col    = lane & 15;
    const int q      = lane >> 4;
    const int ntbase = wid * 2;                     // wave's nt tile base
    const int t0w    = (int)blockIdx.x * TOK_PER_BLK;

    // h accumulators (C-frag layout): hacc[mt][ntl] -> token mt*16+q*4+r,
    // channel (ntbase+ntl)*16+col
    floatx4 hacc[2][2];
    #pragma unroll
    for (int ntl = 0; ntl < 2; ++ntl) {
        const int j = (ntbase + ntl) * 16 + col;
        const float b = b_in[j] + b_init[j] + b_dssp[j];
        floatx4 v = { b, b, b, b };
        hacc[0][ntl] = v; hacc[1][ntl] = v;
    }

    auto loadA = [&](const float* __restrict__ src, int C, int kg, float4 (&X)[2][2]) {
        #pragma unroll
        for (int mt = 0; mt < 2; ++mt) {
            const float* p = src + (size_t)(t0w + mt * 16 + col) * C + kg * 32 + q * 8;
            X[mt][0] = *(const float4*)p;
            X[mt][1] = *(const float4*)(p + 4);
        }
    };

    // ---- input segments: one rolled, software-pipelined kg loop ----
    #pragma unroll 1
    for (int seg = 0; seg < 3; ++seg) {
        const float* src = (seg == 0) ? s : (seg == 1) ? s_init : dssp;
        const int C   = (seg == 2) ? CDSSP : CIN;
        const int NKG = C >> 5;
        const int K8  = C >> 3;
        const bf16_t* plane = wsb +
            (size_t)((seg == 0) ? U_SIN : (seg == 1) ? U_SINIT : U_DSSP) * 8;

        float4 XA[2][2][2];
        BF2 B[2];
        loadA(src, C, 0, XA[0]);
        loadB(plane, K8, 0, ntbase, col, q, B[0]);
        #pragma unroll 1
        for (int kg = 0; kg < NKG; kg += 2) {
            if (kg + 1 < NKG) { loadA(src, C, kg + 1, XA[1]); loadB(plane, K8, kg + 1, ntbase, col, q, B[1]); }
            bf16x8 ahi[2], alo[2];
            packXA(XA[0], ahi, alo);
            mfma_step(ahi, alo, B[0], hacc);
            if (kg + 2 < NKG) { loadA(src, C, kg + 2, XA[0]); loadB(plane, K8, kg + 2, ntbase, col, q, B[0]); }
            if (kg + 1 < NKG) {
                packXA(XA[1], ahi, alo);
                mfma_step(ahi, alo, B[1], hacc);
            }
        }
    }

    // C-layout -> packed relu act plane. Leading barrier: previous readers done
    // before overwrite; trailing barrier: writes visible to all waves.
    auto exchange = [&](floatx4 (&ac)[2][2]) {
        __syncthreads();
        #pragma unroll
        for (int mt = 0; mt < 2; ++mt)
        #pragma unroll
        for (int ntl = 0; ntl < 2; ++ntl)
        #pragma unroll
        for (int r = 0; r < 4; ++r) {
            const float x = fmaxf(ac[mt][ntl][r], 0.f);
            const bf16_t h = (bf16_t)x;
            const bf16_t l = (bf16_t)(x - (float)h);
            A[mt * 16 + q * 4 + r][(ntbase + ntl) * 16 + col] =
                (uint32_t)bf16_bits(h) | ((uint32_t)bf16_bits(l) << 16);
        }
        __syncthreads();
    };

    #pragma unroll 1
    for (int rb = 0; rb < NBLK; ++rb) {
        exchange(hacc);                               // A = relu(h)
        floatx4 vacc[2][2];
        #pragma unroll
        for (int ntl = 0; ntl < 2; ++ntl) {
            const float b = b1[rb * CHID + (ntbase + ntl) * 16 + col];
            floatx4 v = { b, b, b, b };
            vacc[0][ntl] = v; vacc[1][ntl] = v;
        }
        hidden_pass(A, wsb + ((size_t)U_W1 + rb * 4096) * 8, ntbase, col, q, vacc);

        exchange(vacc);                               // A = relu(v)
        #pragma unroll
        for (int ntl = 0; ntl < 2; ++ntl) {
            const float b = b2[rb * CHID + (ntbase + ntl) * 16 + col];
            #pragma unroll
            for (int mt = 0; mt < 2; ++mt) {
                floatx4 tt = hacc[mt][ntl];
                tt[0] += b; tt[1] += b; tt[2] += b; tt[3] += b;
                hacc[mt][ntl] = tt;
            }
        }
        hidden_pass(A, wsb + ((size_t)U_W2 + rb * 4096) * 8, ntbase, col, q, hacc);
    }
    exchange(hacc);                                   // A = relu(h_final)

    // ---- head: 7 fp32 dots/token. Every wave computes from the shared plane
    // (identical values, runs in parallel); wave 0 writes the half-0 outputs,
    // wave 1 writes c4. Shuffle for av/bv stays intra-wave.
    const int t    = lane & 31;
    const int half = lane >> 5;
    float d0v, d1v, d2v, d3v;
    const float *w0, *w1, *w2, *w3;
    if (half == 0) {
        w0 = W_out;          w1 = W_out + CHID; w2 = W_out + 2*CHID; w3 = W_out + 3*CHID;
        d0v = b_out[0]; d1v = b_out[1]; d2v = b_out[2]; d3v = b_out[3];
    } else {
        w0 = W_out + 4*CHID; w1 = W_mult;       w2 = W_mult + CHID;  w3 = W_out;
        d0v = b_out[4]; d1v = b_mult[0]; d2v = b_mult[1]; d3v = 0.f;
    }
    #pragma unroll 1
    for (int k = 0; k < CHID; ++k) {
        const uint32_t pk = A[t][k];
        const float x = (float)bits_bf16(pk & 0xffffu) + (float)bits_bf16(pk >> 16);
        d0v = fmaf(x, w0[k], d0v);
        d1v = fmaf(x, w1[k], d1v);
        d2v = fmaf(x, w2[k], d2v);
        d3v = fmaf(x, w3[k], d3v);
    }
    const float av = __shfl(d1v, 32 + t);
    const float bv = __shfl(d2v, 32 + t);
    const int g = t0w + t;
    if (wid == 0 && half == 0) {
        band[g]            = softplus_f(d0v) * softplus_f(av) + softplus_f(bv);
        band[NTOK + g]     = d1v;   // c1
        band[2*NTOK + g]   = d2v;   // c2
        band[3*NTOK + g]   = d3v;   // c3
    } else if (wid == 1 && half == 1) {
        band[4*NTOK + g]   = d0v;   // c4
    }
}

// ---- fill + patch fused: each block zeroes 8 full rows (128 KB) with
// nontemporal stores, barriers (drains vmcnt), then patches its own rows'
// <=3 diagonal cells. One dispatch instead of two. ----
__global__ __launch_bounds__(256) void fill_patch(
    const float* __restrict__ band, const float* __restrict__ p_sm,
    float* __restrict__ out)
{
    const int bb = (int)blockIdx.x;                  // 0..2047, 8 rows each
    floatx4* dst = (floatx4*)(out + (size_t)bb * 32768);
    const floatx4 z = { 0.f, 0.f, 0.f, 0.f };
    #pragma unroll 1
    for (int i = (int)threadIdx.x; i < 8192; i += 256)
        __builtin_nontemporal_store(z, dst + i);
    __syncthreads();   // vmcnt(0) drain + barrier: zeros ordered before patches
    const int r = (int)threadIdx.x;
    if (r < 8) {
        const int g = bb * 8 + r;                    // global row 0..16383
        const int b = g >> 12;
        const int i = g & (N_SEQ - 1);
        const float sm = *p_sm;
        const size_t rowbase = (size_t)b * N_SEQ * N_SEQ + (size_t)i * N_SEQ;
        out[rowbase + i] = sm * band[g];
        if (i >= 1) out[rowbase + i - 1] = sm * (band[NTOK + g] + band[3*NTOK + g - 1]);
        if (i >= 2) out[rowbase + i - 2] = sm * (band[2*NTOK + g] + band[4*NTOK + g - 2]);
    }
}

extern "C" void kernel_launch(void* const* d_in, const int* in_sizes, int n_in,
                              void* d_out, int out_size, void* d_ws, size_t ws_size,
                              hipStream_t stream)
{
    const float* s      = (const float*)d_in[0];
    const float* s_init = (const float*)d_in[1];
    const float* dssp   = (const float*)d_in[2];
    const float* W_in   = (const float*)d_in[3];
    const float* b_in   = (const float*)d_in[4];
    const float* W_init = (const float*)d_in[5];
    const float* b_initp= (const float*)d_in[6];
    const float* W_dssp = (const float*)d_in[7];
    const float* b_dsspp= (const float*)d_in[8];
    const float* W1     = (const float*)d_in[9];
    const float* b1     = (const float*)d_in[10];
    const float* W2     = (const float*)d_in[11];
    const float* b2     = (const float*)d_in[12];
    const float* W_out  = (const float*)d_in[13];
    const float* b_out  = (const float*)d_in[14];
    const float* W_mult = (const float*)d_in[15];
    const float* b_mult = (const float*)d_in[16];
    const float* sm     = (const float*)d_in[17];
    bf16_t* wsb  = (bf16_t*)d_ws;
    float*  band = (float*)d_ws + BAND_OFF;
    float*  out  = (float*)d_out;

    prep_weights<<<116, 256, 0, stream>>>(W_in, W_init, W_dssp, W1, W2, wsb);

    mlp_kernel<<<MLP_BLOCKS, 256, 0, stream>>>(
        s, s_init, dssp, b_in, b_initp, b_dsspp, b1, b2,
        W_out, b_out, W_mult, b_mult, (const bf16_t*)wsb, band);

    fill_patch<<<2048, 256, 0, stream>>>(band, sm, out);
}

// Round 4
// 394.940 us; speedup vs baseline: 1.0060x; 1.0060x over previous
//
#include <hip/hip_runtime.h>
#include <math.h>

typedef __bf16 bf16_t;
typedef bf16_t bf16x8 __attribute__((ext_vector_type(8)));
typedef float  floatx4 __attribute__((ext_vector_type(4)));

constexpr int N_SEQ = 4096, BSZ = 4, CIN = 384, CDSSP = 64, CHID = 128, NBLK = 4;
constexpr int NTOK = BSZ * N_SEQ;                       // 16384
constexpr int TOK_PER_BLK = 32;
constexpr int MLP_BLOCKS  = NTOK / TOK_PER_BLK;         // 512 blocks, 4 waves each

// ---- wsb layout in 16-byte units (1 unit = 8 bf16), per matrix:
// hi plane (128*K8 units) || lo plane. Within a plane, element (j, k8) with
// nt=j>>4, col=j&15, kg=k8>>2, q=k8&3 lives at unit  nt*(16*K8) + kg*64 + col*4 + q.
// -> a wave's B-frag load for (nt,kg) is 64 lanes x 16 B CONTIGUOUS (1 KB).
constexpr int U_SIN   = 0;                 // W_in:   plane 6144 u, total 12288
constexpr int U_SINIT = 12288;             // W_init: total 12288
constexpr int U_DSSP  = 24576;             // W_dssp: plane 1024 u, total 2048
constexpr int U_W1    = 26624;             // 4 * 4096
constexpr int U_W2    = 43008;             // 4 * 4096
constexpr int U_END   = 59392;             // 950272 B
constexpr int BAND_OFF = U_END * 4;        // float index into d_ws for band arrays

__device__ __forceinline__ float softplus_f(float x) {
    return fmaxf(x, 0.f) + log1pf(expf(-fabsf(x)));
}
__device__ __forceinline__ unsigned short bf16_bits(bf16_t h) {
    union { bf16_t b; unsigned short u; } c; c.b = h; return c.u;
}
__device__ __forceinline__ bf16_t bits_bf16(unsigned int u) {
    union { unsigned short u; bf16_t b; } c; c.u = (unsigned short)u; return c.b;
}
__device__ __forceinline__ floatx4 mfma16(bf16x8 a, bf16x8 b, floatx4 c) {
    return __builtin_amdgcn_mfma_f32_16x16x32_bf16(a, b, c, 0, 0, 0);
}

// ---- prep: split weights into bf16 hi/lo, write coalesced-B-frag image ----
__global__ __launch_bounds__(256) void prep_weights(
    const float* __restrict__ Win, const float* __restrict__ Winit,
    const float* __restrict__ Wd,  const float* __restrict__ W1,
    const float* __restrict__ W2,  bf16_t* __restrict__ wsb)
{
    const int t = (int)blockIdx.x * 256 + (int)threadIdx.x;   // 0..29695
    const float* src; int K, hi_base, plane, u;
    if (t < 6144)       { src = Win;   K = CIN;   hi_base = U_SIN;   plane = 6144; u = t; }
    else if (t < 12288) { src = Winit; K = CIN;   hi_base = U_SINIT; plane = 6144; u = t - 6144; }
    else if (t < 13312) { src = Wd;    K = CDSSP; hi_base = U_DSSP;  plane = 1024; u = t - 12288; }
    else if (t < 21504) { const int tt = t - 13312, rb = tt >> 11; u = tt & 2047;
                          src = W1 + (size_t)rb * CHID * CHID; K = CHID;
                          hi_base = U_W1 + rb * 4096; plane = 2048; }
    else                { const int tt = t - 21504, rb = tt >> 11; u = tt & 2047;
                          src = W2 + (size_t)rb * CHID * CHID; K = CHID;
                          hi_base = U_W2 + rb * 4096; plane = 2048; }
    const int K8 = K >> 3;
    const int nt = u / (16 * K8);
    const int r  = u - nt * 16 * K8;
    const int kg = r >> 6, r2 = r & 63, c = r2 >> 2, qq = r2 & 3;
    const int j = nt * 16 + c, k8 = kg * 4 + qq;
    const float* sp = src + (size_t)j * K + k8 * 8;
    const float4 a = *(const float4*)sp;
    const float4 b = *(const float4*)(sp + 4);
    const float xs[8] = { a.x, a.y, a.z, a.w, b.x, b.y, b.z, b.w };
    bf16x8 vh, vl;
    #pragma unroll
    for (int i = 0; i < 8; ++i) {
        const float x = xs[i];
        const bf16_t h = (bf16_t)x;
        vh[i] = h; vl[i] = (bf16_t)(x - (float)h);
    }
    *(bf16x8*)(wsb + ((size_t)hi_base + u) * 8)         = vh;
    *(bf16x8*)(wsb + ((size_t)hi_base + plane + u) * 8) = vl;
}

// ---- B-frag register set: hi/lo for the wave's 2 nt tiles of one kg ----
struct BF2 { bf16x8 h[2]; bf16x8 l[2]; };

__device__ __forceinline__ void loadB(const bf16_t* __restrict__ plane, int K8,
                                      int kg, int ntbase, int col, int q, BF2& B) {
    const size_t lo  = (size_t)128 * K8 * 8;     // lo plane offset (elements)
    const size_t nts = (size_t)16 * K8 * 8;      // nt step (elements)
    const bf16_t* base = plane + (size_t)(kg * 64 + col * 4 + q) * 8
                               + (size_t)ntbase * nts;
    #pragma unroll
    for (int nt = 0; nt < 2; ++nt) {
        B.h[nt] = *(const bf16x8*)(base + nt * nts);
        B.l[nt] = *(const bf16x8*)(base + nt * nts + lo);
    }
}

__device__ __forceinline__ void mfma_step(const bf16x8 (&ahi)[2], const bf16x8 (&alo)[2],
                                          const BF2& B, floatx4 (&ac)[2][2]) {
    #pragma unroll
    for (int nt = 0; nt < 2; ++nt)
        #pragma unroll
        for (int mt = 0; mt < 2; ++mt) {
            ac[mt][nt] = mfma16(ahi[mt], B.h[nt], ac[mt][nt]);
            ac[mt][nt] = mfma16(alo[mt], B.h[nt], ac[mt][nt]);
            ac[mt][nt] = mfma16(ahi[mt], B.l[nt], ac[mt][nt]);
        }
}

__device__ __forceinline__ void packXA(const float4 (&X)[2][2],
                                       bf16x8 (&ahi)[2], bf16x8 (&alo)[2]) {
    #pragma unroll
    for (int mt = 0; mt < 2; ++mt) {
        const float xs[8] = { X[mt][0].x, X[mt][0].y, X[mt][0].z, X[mt][0].w,
                              X[mt][1].x, X[mt][1].y, X[mt][1].z, X[mt][1].w };
        #pragma unroll
        for (int i = 0; i < 8; ++i) {
            const float r = fmaxf(xs[i], 0.f);
            const bf16_t h = (bf16_t)r;
            ahi[mt][i] = h;
            alo[mt][i] = (bf16_t)(r - (float)h);
        }
    }
}

// A-frags from the block-shared Act plane (packed hi|lo per k)
__device__ __forceinline__ void ldsA(const uint32_t (*A)[132], int kg, int col, int q,
                                     bf16x8 (&ahi)[2], bf16x8 (&alo)[2]) {
    #pragma unroll
    for (int mt = 0; mt < 2; ++mt) {
        const uint32_t* p = &A[mt * 16 + col][kg * 32 + q * 8];
        const uint4 u0 = *(const uint4*)p;
        const uint4 u1 = *(const uint4*)(p + 4);
        const uint32_t uu[8] = { u0.x, u0.y, u0.z, u0.w, u1.x, u1.y, u1.z, u1.w };
        union { uint32_t u[4]; bf16x8 v; } ch, cl;
        #pragma unroll
        for (int i = 0; i < 4; ++i) {
            ch.u[i] = (uu[2*i] & 0xffffu) | (uu[2*i+1] << 16);
            cl.u[i] = (uu[2*i] >> 16) | (uu[2*i+1] & 0xffff0000u);
        }
        ahi[mt] = ch.v; alo[mt] = cl.v;
    }
}

// hidden matmul (K=128), rolled kg loop, B double-buffered
__device__ __forceinline__ void hidden_pass(const uint32_t (*A)[132],
    const bf16_t* __restrict__ plane, int ntbase, int col, int q, floatx4 (&ac)[2][2])
{
    BF2 B[2];
    loadB(plane, 16, 0, ntbase, col, q, B[0]);
    #pragma unroll 1
    for (int kg = 0; kg < 4; kg += 2) {
        loadB(plane, 16, kg + 1, ntbase, col, q, B[1]);
        bf16x8 ahi[2], alo[2];
        ldsA(A, kg, col, q, ahi, alo);
        mfma_step(ahi, alo, B[0], ac);
        if (kg + 2 < 4) loadB(plane, 16, kg + 2, ntbase, col, q, B[0]);
        ldsA(A, kg + 1, col, q, ahi, alo);
        mfma_step(ahi, alo, B[1], ac);
    }
}

// LDS-only barrier: orders ds_write -> ds_read across waves WITHOUT draining
// vmcnt (so in-flight nontemporal zero-stores are never forced to complete
// at a barrier; __syncthreads would emit s_waitcnt vmcnt(0)).
__device__ __forceinline__ void lds_barrier() {
    asm volatile("s_waitcnt lgkmcnt(0)" ::: "memory");
    __builtin_amdgcn_s_barrier();
    asm volatile("" ::: "memory");
}

// ---- MLP fused with output zero-fill: 512 blocks x 4 waves; wave w owns
// output channels [w*32, w*32+32); all waves share one 32-token act plane.
// Each block ALSO zeroes its own 32 output rows (512 KB) with fire-and-forget
// nontemporal stores interleaved between compute phases: the 262 MB write
// stream drains at the HBM write ceiling while MFMA/VALU run, hiding the
// whole compute cost under the compulsory writes. ----
__global__ __launch_bounds__(256) void mlp_kernel(
    const float* __restrict__ s, const float* __restrict__ s_init,
    const float* __restrict__ dssp,
    const float* __restrict__ b_in, const float* __restrict__ b_init,
    const float* __restrict__ b_dssp,
    const float* __restrict__ b1, const float* __restrict__ b2,
    const float* __restrict__ W_out, const float* __restrict__ b_out,
    const float* __restrict__ W_mult, const float* __restrict__ b_mult,
    const bf16_t* __restrict__ wsb, float* __restrict__ band,
    float* __restrict__ out)
{
    __shared__ uint32_t A[32][132];                 // 16.9 KB, block-shared act plane

    const int wid    = (int)threadIdx.x >> 6;       // 0..3
    const int lane   = (int)threadIdx.x & 63;
    const int col    = lane & 15;
    const int q      = lane >> 4;
    const int ntbase = wid * 2;                     // wave's nt tile base
    const int t0w    = (int)blockIdx.x * TOK_PER_BLK;

    // ---- zero-fill state: this block owns rows [t0w, t0w+32) = 512 KB ----
    floatx4* zdst = (floatx4*)(out + (size_t)blockIdx.x * (TOK_PER_BLK * N_SEQ));
    const floatx4 z4 = { 0.f, 0.f, 0.f, 0.f };
    int zc = 0;                                     // 0..128 float4-stores/thread
    auto zburst = [&](int n) {
        #pragma unroll 1
        for (int i = 0; i < n; ++i) {
            if (zc >= 128) break;
            __builtin_nontemporal_store(z4, zdst + (size_t)zc * 256 + (int)threadIdx.x);
            ++zc;
        }
    };

    // h accumulators (C-frag layout): hacc[mt][ntl] -> token mt*16+q*4+r,
    // channel (ntbase+ntl)*16+col
    floatx4 hacc[2][2];
    #pragma unroll
    for (int ntl = 0; ntl < 2; ++ntl) {
        const int j = (ntbase + ntl) * 16 + col;
        const float b = b_in[j] + b_init[j] + b_dssp[j];
        floatx4 v = { b, b, b, b };
        hacc[0][ntl] = v; hacc[1][ntl] = v;
    }

    auto loadA = [&](const float* __restrict__ src, int C, int kg, float4 (&X)[2][2]) {
        #pragma unroll
        for (int mt = 0; mt < 2; ++mt) {
            const float* p = src + (size_t)(t0w + mt * 16 + col) * C + kg * 32 + q * 8;
            X[mt][0] = *(const float4*)p;
            X[mt][1] = *(const float4*)(p + 4);
        }
    };

    // ---- input segments: one rolled, software-pipelined kg loop ----
    #pragma unroll 1
    for (int seg = 0; seg < 3; ++seg) {
        const float* src = (seg == 0) ? s : (seg == 1) ? s_init : dssp;
        const int C   = (seg == 2) ? CDSSP : CIN;
        const int NKG = C >> 5;
        const int K8  = C >> 3;
        const bf16_t* plane = wsb +
            (size_t)((seg == 0) ? U_SIN : (seg == 1) ? U_SINIT : U_DSSP) * 8;

        float4 XA[2][2][2];
        BF2 B[2];
        loadA(src, C, 0, XA[0]);
        loadB(plane, K8, 0, ntbase, col, q, B[0]);
        #pragma unroll 1
        for (int kg = 0; kg < NKG; kg += 2) {
            if (kg + 1 < NKG) { loadA(src, C, kg + 1, XA[1]); loadB(plane, K8, kg + 1, ntbase, col, q, B[1]); }
            bf16x8 ahi[2], alo[2];
            packXA(XA[0], ahi, alo);
            mfma_step(ahi, alo, B[0], hacc);
            if (kg + 2 < NKG) { loadA(src, C, kg + 2, XA[0]); loadB(plane, K8, kg + 2, ntbase, col, q, B[0]); }
            if (kg + 1 < NKG) {
                packXA(XA[1], ahi, alo);
                mfma_step(ahi, alo, B[1], hacc);
            }
            zburst(6);   // 13 iterations total -> up to 78 stores issued here
        }
    }

    // C-layout -> packed relu act plane. Leading barrier: previous readers done
    // before overwrite; trailing barrier: writes visible to all waves.
    auto exchange = [&](floatx4 (&ac)[2][2]) {
        lds_barrier();
        #pragma unroll
        for (int mt = 0; mt < 2; ++mt)
        #pragma unroll
        for (int ntl = 0; ntl < 2; ++ntl)
        #pragma unroll
        for (int r = 0; r < 4; ++r) {
            const float x = fmaxf(ac[mt][ntl][r], 0.f);
            const bf16_t h = (bf16_t)x;
            const bf16_t l = (bf16_t)(x - (float)h);
            A[mt * 16 + q * 4 + r][(ntbase + ntl) * 16 + col] =
                (uint32_t)bf16_bits(h) | ((uint32_t)bf16_bits(l) << 16);
        }
        lds_barrier();
    };

    #pragma unroll 1
    for (int rb = 0; rb < NBLK; ++rb) {
        exchange(hacc);                               // A = relu(h)
        zburst(3);
        floatx4 vacc[2][2];
        #pragma unroll
        for (int ntl = 0; ntl < 2; ++ntl) {
            const float b = b1[rb * CHID + (ntbase + ntl) * 16 + col];
            floatx4 v = { b, b, b, b };
            vacc[0][ntl] = v; vacc[1][ntl] = v;
        }
        hidden_pass(A, wsb + ((size_t)U_W1 + rb * 4096) * 8, ntbase, col, q, vacc);
        zburst(3);

        exchange(vacc);                               // A = relu(v)
        zburst(3);
        #pragma unroll
        for (int ntl = 0; ntl < 2; ++ntl) {
            const float b = b2[rb * CHID + (ntbase + ntl) * 16 + col];
            #pragma unroll
            for (int mt = 0; mt < 2; ++mt) {
                floatx4 tt = hacc[mt][ntl];
                tt[0] += b; tt[1] += b; tt[2] += b; tt[3] += b;
                hacc[mt][ntl] = tt;
            }
        }
        hidden_pass(A, wsb + ((size_t)U_W2 + rb * 4096) * 8, ntbase, col, q, hacc);
        zburst(3);
    }
    exchange(hacc);                                   // A = relu(h_final)
    zburst(128);                                      // flush any remainder

    // ---- head: 7 fp32 dots/token. Every wave computes from the shared plane
    // (identical values, runs in parallel); wave 0 writes the half-0 outputs,
    // wave 1 writes c4. Shuffle for av/bv stays intra-wave.
    const int t    = lane & 31;
    const int half = lane >> 5;
    float d0v, d1v, d2v, d3v;
    const float *w0, *w1, *w2, *w3;
    if (half == 0) {
        w0 = W_out;          w1 = W_out + CHID; w2 = W_out + 2*CHID; w3 = W_out + 3*CHID;
        d0v = b_out[0]; d1v = b_out[1]; d2v = b_out[2]; d3v = b_out[3];
    } else {
        w0 = W_out + 4*CHID; w1 = W_mult;       w2 = W_mult + CHID;  w3 = W_out;
        d0v = b_out[4]; d1v = b_mult[0]; d2v = b_mult[1]; d3v = 0.f;
    }
    #pragma unroll 1
    for (int k = 0; k < CHID; ++k) {
        const uint32_t pk = A[t][k];
        const float x = (float)bits_bf16(pk & 0xffffu) + (float)bits_bf16(pk >> 16);
        d0v = fmaf(x, w0[k], d0v);
        d1v = fmaf(x, w1[k], d1v);
        d2v = fmaf(x, w2[k], d2v);
        d3v = fmaf(x, w3[k], d3v);
    }
    const float av = __shfl(d1v, 32 + t);
    const float bv = __shfl(d2v, 32 + t);
    const int g = t0w + t;
    if (wid == 0 && half == 0) {
        band[g]            = softplus_f(d0v) * softplus_f(av) + softplus_f(bv);
        band[NTOK + g]     = d1v;   // c1
        band[2*NTOK + g]   = d2v;   // c2
        band[3*NTOK + g]   = d3v;   // c3
    } else if (wid == 1 && half == 1) {
        band[4*NTOK + g]   = d0v;   // c4
    }
}

// ---- patch the three diagonals (each cell fully overwritten; no RMW).
// Runs after mlp_kernel, whose completion guarantees all zeros landed. ----
__global__ __launch_bounds__(256) void band_patch(
    const float* __restrict__ band, const float* __restrict__ p_sm,
    float* __restrict__ out)
{
    const int g = (int)blockIdx.x * 256 + (int)threadIdx.x;   // 0..16383
    const int b = g >> 12;
    const int i = g & (N_SEQ - 1);
    const float sm = *p_sm;
    const size_t rowbase = (size_t)b * N_SEQ * N_SEQ + (size_t)i * N_SEQ;
    out[rowbase + i] = sm * band[g];
    if (i >= 1) out[rowbase + i - 1] = sm * (band[NTOK + g] + band[3*NTOK + g - 1]);
    if (i >= 2) out[rowbase + i - 2] = sm * (band[2*NTOK + g] + band[4*NTOK + g - 2]);
}

extern "C" void kernel_launch(void* const* d_in, const int* in_sizes, int n_in,
                              void* d_out, int out_size, void* d_ws, size_t ws_size,
                              hipStream_t stream)
{
    const float* s      = (const float*)d_in[0];
    const float* s_init = (const float*)d_in[1];
    const float* dssp   = (const float*)d_in[2];
    const float* W_in   = (const float*)d_in[3];
    const float* b_in   = (const float*)d_in[4];
    const float* W_init = (const float*)d_in[5];
    const float* b_initp= (const float*)d_in[6];
    const float* W_dssp = (const float*)d_in[7];
    const float* b_dsspp= (const float*)d_in[8];
    const float* W1     = (const float*)d_in[9];
    const float* b1     = (const float*)d_in[10];
    const float* W2     = (const float*)d_in[11];
    const float* b2     = (const float*)d_in[12];
    const float* W_out  = (const float*)d_in[13];
    const float* b_out  = (const float*)d_in[14];
    const float* W_mult = (const float*)d_in[15];
    const float* b_mult = (const float*)d_in[16];
    const float* sm     = (const float*)d_in[17];
    bf16_t* wsb  = (bf16_t*)d_ws;
    float*  band = (float*)d_ws + BAND_OFF;
    float*  out  = (float*)d_out;

    prep_weights<<<116, 256, 0, stream>>>(W_in, W_init, W_dssp, W1, W2, wsb);

    mlp_kernel<<<MLP_BLOCKS, 256, 0, stream>>>(
        s, s_init, dssp, b_in, b_initp, b_dsspp, b1, b2,
        W_out, b_out, W_mult, b_mult, (const bf16_t*)wsb, band, out);

    band_patch<<<NTOK / 256, 256, 0, stream>>>(band, sm, out);
}